// Round 2
// baseline (1081.761 us; speedup 1.0000x reference)
//
#include <hip/hip_runtime.h>
#include <math.h>

#define HW_N   147456           // 384*384
#define NCH    32
#define NBATCH 8

// ---------------------------------------------------------------------------
// Phase 1: per-batch channel gram G[b][i][j] = sum_hw q[b,i,hw]*v[b,j,hw]
//          plus channel sums sq[b][c], sv[b][c].
// Barrier-free register streaming: grid (144, 8), block 256 (4 waves).
// Wave owns 256 positions; lane: pg = lane>>4 (float4 position group),
// jg = lane&15 (v channels 2jg, 2jg+1). Per 16-pos step: 2 coalesced v loads
// (16 x 64B lines) + 32 q broadcast loads (1 x 64B line each, 16-way bcast).
// acc[i][jj] in VGPRs; one barrier at the end for the cross-wave reduce.
// ---------------------------------------------------------------------------
__global__ __launch_bounds__(256, 3) void gram_kernel(
    const float* __restrict__ q, const float* __restrict__ v,
    float* __restrict__ G, float* __restrict__ sq, float* __restrict__ sv)
{
    __shared__ float red[4][1024];

    const int b    = blockIdx.y;
    const int t    = threadIdx.x;
    const int w    = t >> 6;
    const int lane = t & 63;
    const int jg   = lane & 15;
    const int pg   = lane >> 4;

    const float* qb = q + (size_t)b * NCH * HW_N;
    const float* vb = v + (size_t)b * NCH * HW_N;
    const float* v0r = vb + (size_t)(2 * jg) * HW_N;
    const float* v1r = vb + (size_t)(2 * jg + 1) * HW_N;

    float acc0[32], acc1[32], sumq[32];
#pragma unroll
    for (int i = 0; i < 32; ++i) { acc0[i] = 0.f; acc1[i] = 0.f; sumq[i] = 0.f; }
    float sv0 = 0.f, sv1 = 0.f;

    const int PW = blockIdx.x * 1024 + w * 256;

    for (int s = 0; s < 16; ++s) {
        const int p = PW + s * 16 + 4 * pg;
        const float4 vv0 = *(const float4*)(v0r + p);
        const float4 vv1 = *(const float4*)(v1r + p);
        sv0 += vv0.x + vv0.y + vv0.z + vv0.w;
        sv1 += vv1.x + vv1.y + vv1.z + vv1.w;
#pragma unroll
        for (int i = 0; i < 32; ++i) {
            const float4 qi = *(const float4*)(qb + (size_t)i * HW_N + p);
            acc0[i] += qi.x * vv0.x + qi.y * vv0.y + qi.z * vv0.z + qi.w * vv0.w;
            acc1[i] += qi.x * vv1.x + qi.y * vv1.y + qi.z * vv1.z + qi.w * vv1.w;
            sumq[i] += qi.x + qi.y + qi.z + qi.w;
        }
    }

    // ---- reduce over pg (lane bits 4,5); jg lanes hold distinct channels ----
#pragma unroll
    for (int i = 0; i < 32; ++i) {
        acc0[i] += __shfl_xor(acc0[i], 16); acc0[i] += __shfl_xor(acc0[i], 32);
        acc1[i] += __shfl_xor(acc1[i], 16); acc1[i] += __shfl_xor(acc1[i], 32);
        // sumq is identical across jg (same positions per pg); pg-reduce gives
        // the exact wave total on every lane — no scaling needed.
        sumq[i] += __shfl_xor(sumq[i], 16); sumq[i] += __shfl_xor(sumq[i], 32);
    }
    sv0 += __shfl_xor(sv0, 16); sv0 += __shfl_xor(sv0, 32);
    sv1 += __shfl_xor(sv1, 16); sv1 += __shfl_xor(sv1, 32);

    if (lane < 16) {
#pragma unroll
        for (int i = 0; i < 32; ++i)
            *(float2*)&red[w][i * 32 + 2 * jg] = make_float2(acc0[i], acc1[i]);
        atomicAdd(&sv[b * 32 + 2 * jg],     sv0);
        atomicAdd(&sv[b * 32 + 2 * jg + 1], sv1);
    }
    if (lane == 0) {
#pragma unroll
        for (int i = 0; i < 32; ++i)
            atomicAdd(&sq[b * 32 + i], sumq[i]);
    }
    __syncthreads();
#pragma unroll
    for (int k = 0; k < 4; ++k) {
        int idx = t + k * 256;
        float s = red[0][idx] + red[1][idx] + red[2][idx] + red[3][idx];
        atomicAdd(&G[b * 1024 + idx], s);
    }
}

// ---------------------------------------------------------------------------
// Phase 2: logits -> softmax -> Mt = (wo@S@wa + I)^T, e = wo@(S@ba) + bo.
// grid NBATCH x 1024 threads; thread (i = t>>5, j = t&31). Tiny.
// ---------------------------------------------------------------------------
__global__ __launch_bounds__(1024) void attn_kernel(
    const float* __restrict__ G, const float* __restrict__ sq, const float* __restrict__ sv,
    const float* __restrict__ wa, const float* __restrict__ ba,
    const float* __restrict__ wb, const float* __restrict__ bb,
    const float* __restrict__ wc, const float* __restrict__ bc,
    const float* __restrict__ wo, const float* __restrict__ bo,
    float* __restrict__ Mt, float* __restrict__ e)
{
    const int b = blockIdx.x;
    const int t = threadIdx.x;
    const int i = t >> 5;
    const int j = t & 31;

    __shared__ float Gs[32][33], T[32][33], Ss[32][33], sba[32];

    Gs[i][j] = G[b * 1024 + i * 32 + j];
    __syncthreads();

    // T[i][d] = sum_c wc[i][c] * G[c][d]   (d = j)
    float acc = 0.f;
#pragma unroll
    for (int c = 0; c < 32; ++c) acc += wc[i * 32 + c] * Gs[c][j];
    T[i][j] = acc;
    __syncthreads();

    // logits
    float L = 0.f;
#pragma unroll
    for (int d = 0; d < 32; ++d) L += T[i][d] * wb[j * 32 + d];
    float sqw = 0.f, svw = 0.f;
#pragma unroll
    for (int c = 0; c < 32; ++c) {
        sqw += wc[i * 32 + c] * sq[b * 32 + c];
        svw += wb[j * 32 + c] * sv[b * 32 + c];
    }
    L += bc[i] * svw + bb[j] * sqw + bc[i] * bb[j] * (float)HW_N;

    // softmax across j
    float m = L;
#pragma unroll
    for (int off = 16; off >= 1; off >>= 1) m = fmaxf(m, __shfl_xor(m, off));
    float ex = __expf(L - m);
    float s = ex;
#pragma unroll
    for (int off = 16; off >= 1; off >>= 1) s += __shfl_xor(s, off);
    float S = ex / s;
    Ss[i][j] = S;

    float p = S * ba[j];
#pragma unroll
    for (int off = 16; off >= 1; off >>= 1) p += __shfl_xor(p, off);
    if (j == 0) sba[i] = p;
    __syncthreads();

    // T[i][d] = sum_j S[i][j] * wa[j][d]
    float acc2 = 0.f;
#pragma unroll
    for (int jj = 0; jj < 32; ++jj) acc2 += Ss[i][jj] * wa[jj * 32 + j];
    T[i][j] = acc2;
    __syncthreads();

    // M[o][d] = sum_i wo[o][i] * T[i][d]; store transposed with identity:
    // Mt[d][o] = M[o][d] + (o==d)  -> folds the residual add into phase 3.
    float acc3 = 0.f;
#pragma unroll
    for (int ii = 0; ii < 32; ++ii) acc3 += wo[i * 32 + ii] * T[ii][j];
    Mt[b * 1024 + j * 32 + i] = acc3 + (i == j ? 1.f : 0.f);

    if (j == 0) {
        float ee = bo[i];
#pragma unroll
        for (int ii = 0; ii < 32; ++ii) ee += wo[i * 32 + ii] * sba[ii];
        e[b * 32 + i] = ee;
    }
}

// ---------------------------------------------------------------------------
// Phase 3: out[b,o,p] = sum_d Mt[b][d][o]*v[b,d,p] + e[b][o]   (Mt has +I)
// Barrier-free, LDS-free: grid (288, 8), block 256. Thread owns a float2 of
// positions; streams 32 coalesced v-row loads; M/e are wave-uniform scalar
// loads; 32 coalesced float2 stores.
// ---------------------------------------------------------------------------
__global__ __launch_bounds__(256, 4) void out_kernel(
    const float* __restrict__ v, const float* __restrict__ Mt,
    const float* __restrict__ e, float* __restrict__ out)
{
    const int b = blockIdx.y;
    const int t = threadIdx.x;
    const int p = blockIdx.x * 512 + 2 * t;

    const float* vb  = v   + (size_t)b * NCH * HW_N;
    float*       ob  = out + (size_t)b * NCH * HW_N;
    const float* Mtb = Mt  + b * 1024;   // Mt[d][o], uniform -> s_load
    const float* eb  = e   + b * 32;

    float ax[32], ay[32];
#pragma unroll
    for (int o = 0; o < 32; ++o) { float eo = eb[o]; ax[o] = eo; ay[o] = eo; }

#pragma unroll
    for (int d = 0; d < 32; ++d) {
        const float2 vd = *(const float2*)(vb + (size_t)d * HW_N + p);
#pragma unroll
        for (int o = 0; o < 32; ++o) {
            const float m = Mtb[d * 32 + o];
            ax[o] += m * vd.x;
            ay[o] += m * vd.y;
        }
    }

#pragma unroll
    for (int o = 0; o < 32; ++o)
        *(float2*)(ob + (size_t)o * HW_N + p) = make_float2(ax[o], ay[o]);
}

// ---------------------------------------------------------------------------
extern "C" void kernel_launch(void* const* d_in, const int* in_sizes, int n_in,
                              void* d_out, int out_size, void* d_ws, size_t ws_size,
                              hipStream_t stream) {
    const float* q  = (const float*)d_in[0];
    const float* v  = (const float*)d_in[1];
    const float* wa = (const float*)d_in[2];
    const float* ba = (const float*)d_in[3];
    const float* wb = (const float*)d_in[4];
    const float* bb = (const float*)d_in[5];
    const float* wc = (const float*)d_in[6];
    const float* bc = (const float*)d_in[7];
    const float* wo = (const float*)d_in[8];
    const float* bo = (const float*)d_in[9];
    float* out = (float*)d_out;

    float* G  = (float*)d_ws;            // 8*1024
    float* sq = G + NBATCH * 1024;       // 8*32
    float* sv = sq + NBATCH * 32;        // 8*32
    float* Mt = sv + NBATCH * 32;        // 8*1024 (transposed M + I)
    float* e  = Mt + NBATCH * 1024;      // 8*32

    // ws is poisoned 0xAA before every launch -> zero the atomic accumulators.
    hipMemsetAsync(d_ws, 0, (size_t)(NBATCH * 1024 + 2 * NBATCH * 32) * sizeof(float), stream);

    gram_kernel<<<dim3(144, NBATCH), 256, 0, stream>>>(q, v, G, sq, sv);
    attn_kernel<<<NBATCH, 1024, 0, stream>>>(G, sq, sv, wa, ba, wb, bb, wc, bc, wo, bo, Mt, e);
    out_kernel<<<dim3(288, NBATCH), 256, 0, stream>>>(v, Mt, e, out);
}